// Round 4
// baseline (190.536 us; speedup 1.0000x reference)
//
#include <hip/hip_runtime.h>
#include <hip/hip_bf16.h>
#include <math.h>

// Problem constants (B,C,H,W,O,K,E) = (8,256,64,64,256,3,3)
// weff[b,o,c,tap] = sum_e gates[b,e]*(experts[e,o,c,tap]+experts[e,o,c+256,tap])
// out[b,o,h,w] = sum_{c,dh,dw} q[b,c,h+dh-1,w+dw-1] * weff[b,o,c,dh*3+dw]
//
// Workspace layout (~27.3 MB):
//   [0)        yctx   : 2048 f32
//   [16384)    wf     : bf16 [8 b][9 tap][8 ch][256 o][32 c]     (9,437,184 B)  UNSWIZZLED
//   [9453568)  qT     : bf16 [8 b][8 ch][66 hp][66 wp][32 cl']   (17,842,176 B)
// qT cl' swizzle: group' = (cl>>3) ^ ((wp>>1)&3); keeps ds_read_b128 B-fragment
// reads at free 2-way bank conflicts. wf is read global->VGPR (no LDS), so no swizzle.
//
// conv tiling (R4): block = 128 o x 256 n (4 h-rows x 64 w), 4 waves,
// wave = M64 x N128 -> 32 MFMA/step, A 4 frags (global), B 8 frags (LDS).
// Per-CU per-step traffic: VM 16 KB (256 cyc), LDS 32 KB (~290 cyc),
// matrix 154 cyc/SIMD -> LDS-bound ~50-60% MfmaUtil (was VM-bound 29%).

typedef __bf16 bf16x8 __attribute__((ext_vector_type(8)));
typedef __bf16 bf16x4 __attribute__((ext_vector_type(4)));
typedef float f32x4 __attribute__((ext_vector_type(4)));

#define AS1 __attribute__((address_space(1)))
#define AS3 __attribute__((address_space(3)))

// ---------------- kernel 1: y_ctx[b,c] = mean_{h,w} y ----------------
__global__ __launch_bounds__(64) void yctx_kernel(const float* __restrict__ y,
                                                  float* __restrict__ yctx) {
  int bc = blockIdx.x;  // b*256 + c
  const float4* p = (const float4*)(y + (size_t)bc * 4096);
  int lane = threadIdx.x;
  float s = 0.f;
  for (int i = lane; i < 1024; i += 64) {
    float4 v = p[i];
    s += v.x + v.y + v.z + v.w;
  }
#pragma unroll
  for (int off = 32; off > 0; off >>= 1) s += __shfl_down(s, off, 64);
  if (lane == 0) yctx[bc] = s * (1.f / 4096.f);
}

// ---------------- kernel 2: wf (gates computed in-kernel; folded; bf16) ----------------
__global__ __launch_bounds__(256) void wbuild_kernel(const float* __restrict__ experts,
                                                     const float* __restrict__ yctx,
                                                     const float* __restrict__ gw,
                                                     const float* __restrict__ gb,
                                                     __bf16* __restrict__ wf) {
  int o = blockIdx.x;      // 0..255
  int tid = threadIdx.x;
  __shared__ float sf[3][2304];  // folded experts [e][c*9+tap] (27.6 KB)
  __shared__ float g[8][3];
  __shared__ float lg[24];

#pragma unroll
  for (int e = 0; e < 3; e++) {
    const float4* src = (const float4*)(experts + ((size_t)e * 256 + o) * 4608);
    float4* dstp = (float4*)sf[e];
    for (int i = tid; i < 576; i += 256) {
      float4 a = src[i], bq = src[i + 576];
      float4 r;
      r.x = a.x + bq.x; r.y = a.y + bq.y; r.z = a.z + bq.z; r.w = a.w + bq.w;
      dstp[i] = r;
    }
  }
  if (tid < 24) {  // logits (redundant per block; tiny)
    int b = tid / 3, e = tid - b * 3;
    float s = gb[e];
    for (int c = 0; c < 256; c++)
      s += yctx[b * 256 + c] * (gw[c * 3 + e] + gw[(c + 256) * 3 + e]);
    lg[tid] = s;
  }
  __syncthreads();
  if (tid < 8) {
    float l0 = lg[tid * 3 + 0], l1 = lg[tid * 3 + 1], l2 = lg[tid * 3 + 2];
    float m = fmaxf(l0, fmaxf(l1, l2));
    float e0 = __expf(l0 - m), e1 = __expf(l1 - m), e2 = __expf(l2 - m);
    float inv = 1.f / (e0 + e1 + e2);
    g[tid][0] = e0 * inv; g[tid][1] = e1 * inv; g[tid][2] = e2 * inv;
  }
  __syncthreads();

  // stores: 4 wave-groups each own a (b,tap) stream; bf16x4 per lane
  int grp = tid >> 6, ch = (tid >> 3) & 7, clq = tid & 7;
#pragma unroll 1
  for (int bt = grp; bt < 72; bt += 4) {
    int b = bt / 9, tap = bt - b * 9;
    float g0 = g[b][0], g1 = g[b][1], g2 = g[b][2];
    bf16x4 r;
#pragma unroll
    for (int j = 0; j < 4; j++) {
      int c = ch * 32 + clq * 4 + j;
      float v = g0 * sf[0][c * 9 + tap] + g1 * sf[1][c * 9 + tap] +
                g2 * sf[2][c * 9 + tap];
      r[j] = (__bf16)v;
    }
    *(bf16x4*)(wf + ((((size_t)b * 9 + tap) * 8 + ch) * 256 + o) * 32 + clq * 4) = r;
  }
}

// ---------------- kernel 3: qT (padded, transposed, bf16, B-ready layout) ----------------
__global__ __launch_bounds__(256) void qt_kernel(const float* __restrict__ q,
                                                 __bf16* __restrict__ qT) {
  int bid = blockIdx.x;          // (b*8 + ch)*66 + hp
  int hp = bid % 66;
  int t2 = bid / 66;
  int ch = t2 & 7;
  int b = t2 >> 3;
  __bf16* dst = qT + (((size_t)(b * 8 + ch) * 66 + hp) * 66) * 32;
  int tid = threadIdx.x;
  float4 z4 = {0.f, 0.f, 0.f, 0.f};
  if (hp == 0 || hp == 65) {     // top/bottom zero padding rows: 4224 B
    float4* d4 = (float4*)dst;
    for (int i = tid; i < 264; i += 256) d4[i] = z4;
    return;
  }
  __shared__ float tile2[64][33];  // [w][c]; write banks (w+c)%32 -> free 2-way
  int h = hp - 1;
  {
    int w = tid & 63, ci = tid >> 6;  // ci 0..3
#pragma unroll
    for (int j = 0; j < 8; j++) {
      int c = ci * 8 + j;
      tile2[w][c] = q[(((size_t)b * 256 + ch * 32 + c) * 64 + h) * 64 + w];
    }
  }
  if (tid < 4) ((float4*)dst)[tid] = z4;                       // wp = 0
  else if (tid < 8) ((float4*)(dst + 65 * 32))[tid - 4] = z4;  // wp = 65
  __syncthreads();

  int a = tid & 7, wsl = tid >> 3;    // a: c-quad, wsl: 0..31 (2 w each)
  int cl4 = a * 4;
#pragma unroll
  for (int k = 0; k < 2; k++) {
    int w = wsl * 2 + k, wp = w + 1;
    int clp4 = (((cl4 >> 3) ^ ((wp >> 1) & 3)) << 3) | (cl4 & 7);
    float v0 = tile2[w][cl4 + 0], v1 = tile2[w][cl4 + 1];
    float v2 = tile2[w][cl4 + 2], v3 = tile2[w][cl4 + 3];
    bf16x4 r = {(__bf16)v0, (__bf16)v1, (__bf16)v2, (__bf16)v3};
    *(bf16x4*)(dst + wp * 32 + clp4) = r;
  }
}

// ---------------- kernel 4: MFMA conv — 128x256 tile, wave M64xN128 ----------------
__global__ __launch_bounds__(256, 1) void conv_kernel(const __bf16* __restrict__ qT,
                                                      const __bf16* __restrict__ wf,
                                                      float* __restrict__ out) {
  // Q tile: 6 rows x 66 wp x 32 c x 2B = 25344 B, padded to 28672 (1792 x 16B chunks)
  __shared__ __align__(16) char Qlds[2][28672];
  const int tid = threadIdx.x;
  const int lane = tid & 63;
  const int wv = tid >> 6;
  const int wm = wv >> 1, wn = wv & 1;   // wm: o-half, wn: n-half (2 h-rows)
  const int l15 = lane & 15, qd = lane >> 4;

  const int bid = blockIdx.x;       // 256 blocks
  const int b = bid & 7;            // XCD swizzle: same b -> same XCD
  const int rem = bid >> 3;         // 0..31
  const int o0 = (rem >> 4) * 128;  // {0,128}
  const int h0 = (rem & 15) * 4;    // 0..60

  f32x4 acc[4][8];
  {
    f32x4 z = {0.f, 0.f, 0.f, 0.f};
#pragma unroll
    for (int i = 0; i < 4; i++)
#pragma unroll
      for (int j = 0; j < 8; j++) acc[i][j] = z;
  }

  const char* qT_b = (const char*)qT + (size_t)b * 8 * 66 * 66 * 32 * 2;
  // A-fragment base: lane reads 16 B at ((o0+wm*64+mi*16+l15)*32 + qd*8)*2
  const char* abase = (const char*)wf + ((size_t)b * 9 * 8 * 256 +
                                         (size_t)(o0 + wm * 64 + l15)) * 64 +
                      (size_t)qd * 16;
  bf16x8 acur[4], anxt[4];

  // ---- prologue: stage Q(ch=0) rows hp0=h0..h0+5; load A(tap0,ch0)
  {
    const char* qsrc = qT_b + ((size_t)h0) * 4224;
    for (int i = tid; i < 1792; i += 256) {
      int gi = (i < 1584) ? i : 0;   // clamp tail (pad slots get junk, never read)
      int ub = i - lane;
      __builtin_amdgcn_global_load_lds((const AS1 void*)(qsrc + ((size_t)gi << 4)),
                                       (AS3 void*)(Qlds[0] + ((size_t)ub << 4)),
                                       16, 0, 0);
    }
#pragma unroll
    for (int mi = 0; mi < 4; mi++)
      acur[mi] = *(const bf16x8*)(abase + mi * 1024);
    __syncthreads();
  }

#pragma unroll 1
  for (int ch = 0; ch < 8; ch++) {
    if (ch < 7) {  // prefetch next ch's Q rows — overlaps all 9 taps
      const char* qsrc = qT_b + ((size_t)((ch + 1) * 66 + h0)) * 4224;
      char* qdst = Qlds[(ch + 1) & 1];
      for (int i = tid; i < 1792; i += 256) {
        int gi = (i < 1584) ? i : 0;
        int ub = i - lane;
        __builtin_amdgcn_global_load_lds((const AS1 void*)(qsrc + ((size_t)gi << 4)),
                                         (AS3 void*)(qdst + ((size_t)ub << 4)),
                                         16, 0, 0);
      }
    }
    const char* Qb = Qlds[ch & 1];
#pragma unroll
    for (int tap = 0; tap < 9; tap++) {
      {  // register double-buffer A prefetch (vmcnt-waited at use, no barrier)
        int tapn = (tap == 8) ? 0 : tap + 1;
        int chn = (tap == 8) ? ch + 1 : ch;   // chn==8 on final step: in-bounds, unused
        size_t aoff = ((size_t)(tapn * 8 + chn)) << 14;
#pragma unroll
        for (int mi = 0; mi < 4; mi++)
          anxt[mi] = *(const bf16x8*)(abase + aoff + mi * 1024);
      }
      const int dh = tap / 3, dw = tap - dh * 3;
#pragma unroll
      for (int ni = 0; ni < 8; ni++) {
        int r = wn * 2 + (ni >> 2) + dh;        // 0..5
        int wp = (ni & 3) * 16 + l15 + dw;      // 0..65
        int g = (qd ^ ((wp >> 1) & 3)) << 3;
        bf16x8 bfv = *(const bf16x8*)(Qb + ((r * 66 + wp) * 32 + g) * 2);
#pragma unroll
        for (int mi = 0; mi < 4; mi++)
          acc[mi][ni] = __builtin_amdgcn_mfma_f32_16x16x32_bf16(
              acur[mi], bfv, acc[mi][ni], 0, 0, 0);
      }
#pragma unroll
      for (int mi = 0; mi < 4; mi++) acur[mi] = anxt[mi];
    }
    __syncthreads();  // end of ch: Q(ch+1) drained; buffer reuse safe
  }

  // epilogue: C/D layout col(l15)=w-part, row = qd*4+rr (o)
#pragma unroll
  for (int mi = 0; mi < 4; mi++) {
    int o = o0 + wm * 64 + mi * 16 + qd * 4;
#pragma unroll
    for (int ni = 0; ni < 8; ni++) {
      int h = h0 + wn * 2 + (ni >> 2);
      int w = (ni & 3) * 16 + l15;
#pragma unroll
      for (int rr = 0; rr < 4; rr++)
        out[(((size_t)b * 256 + (o + rr)) * 64 + h) * 64 + w] = acc[mi][ni][rr];
    }
  }
}

extern "C" void kernel_launch(void* const* d_in, const int* in_sizes, int n_in,
                              void* d_out, int out_size, void* d_ws, size_t ws_size,
                              hipStream_t stream) {
  (void)in_sizes; (void)n_in; (void)out_size; (void)ws_size;
  const float* q = (const float*)d_in[0];
  const float* y = (const float*)d_in[1];
  const float* experts = (const float*)d_in[2];
  const float* gate_w = (const float*)d_in[3];
  const float* gate_b = (const float*)d_in[4];
  float* out = (float*)d_out;

  char* ws = (char*)d_ws;
  float* yctx = (float*)ws;                         // 8 KB
  __bf16* wf = (__bf16*)(ws + 16384);               // 9,437,184 B
  __bf16* qT = (__bf16*)(ws + 16384 + 9437184);     // 17,842,176 B

  yctx_kernel<<<2048, 64, 0, stream>>>(y, yctx);
  qt_kernel<<<8 * 8 * 66, 256, 0, stream>>>(q, qT);
  wbuild_kernel<<<256, 256, 0, stream>>>(experts, yctx, gate_w, gate_b, wf);
  conv_kernel<<<256, 256, 0, stream>>>(qT, wf, out);
}

// Round 5
// 182.910 us; speedup vs baseline: 1.0417x; 1.0417x over previous
//
#include <hip/hip_runtime.h>
#include <hip/hip_bf16.h>
#include <math.h>

// Problem constants (B,C,H,W,O,K,E) = (8,256,64,64,256,3,3)
// weff[b,o,c,tap] = sum_e gates[b,e]*(experts[e,o,c,tap]+experts[e,o,c+256,tap])
// out[b,o,h,w] = sum_{c,dh,dw} q[b,c,h+dh-1,w+dw-1] * weff[b,o,c,dh*3+dw]
//
// Workspace layout (~27.3 MB):
//   [0)        yctx   : 2048 f32
//   [8192)     logits : 24 f32
//   [16384)    wf     : bf16 [8 b][9 tap][8 ch][256 o][32 c]     (unswizzled)
//   [9453568)  qT     : bf16 [8 b][8 ch][66 hp][66 wp][32 cl']
// qT cl' swizzle: group' = (cl>>3) ^ ((wp>>1)&3) -> ds_read_b128 at free 2-way.
//
// conv R5: R3 tile (block 128o x 128n = 2 h-rows x 64 w, 4 waves M64xN64,
// 2 blocks/CU) + explicit pipeline: A global loads 2 steps ahead (vmcnt cover
// ~310 cyc > L2 latency), B ds_reads 1 step ahead, B-offset table precomputed.

typedef __bf16 bf16x8 __attribute__((ext_vector_type(8)));
typedef __bf16 bf16x4 __attribute__((ext_vector_type(4)));
typedef float f32x4 __attribute__((ext_vector_type(4)));

#define AS1 __attribute__((address_space(1)))
#define AS3 __attribute__((address_space(3)))

// ---------------- kernel 1: y_ctx[b,c] = mean_{h,w} y ----------------
__global__ __launch_bounds__(64) void yctx_kernel(const float* __restrict__ y,
                                                  float* __restrict__ yctx) {
  int bc = blockIdx.x;  // b*256 + c
  const float4* p = (const float4*)(y + (size_t)bc * 4096);
  int lane = threadIdx.x;
  float s = 0.f;
  for (int i = lane; i < 1024; i += 64) {
    float4 v = p[i];
    s += v.x + v.y + v.z + v.w;
  }
#pragma unroll
  for (int off = 32; off > 0; off >>= 1) s += __shfl_down(s, off, 64);
  if (lane == 0) yctx[bc] = s * (1.f / 4096.f);
}

// ---------------- kernel 2: logits[b,e] ----------------
__global__ __launch_bounds__(64) void logits_kernel(const float* __restrict__ yctx,
                                                    const float* __restrict__ gw,
                                                    const float* __restrict__ gb,
                                                    float* __restrict__ logits) {
  int be = blockIdx.x;  // b*3 + e
  int b = be / 3, e = be - b * 3;
  int lane = threadIdx.x;
  float s = 0.f;
  for (int c = lane; c < 256; c += 64)
    s += yctx[b * 256 + c] * (gw[c * 3 + e] + gw[(c + 256) * 3 + e]);
#pragma unroll
  for (int off = 32; off > 0; off >>= 1) s += __shfl_down(s, off, 64);
  if (lane == 0) logits[be] = s + gb[e];
}

// ---------------- kernel 3: wf (mixed, folded, bf16) ----------------
__global__ __launch_bounds__(256) void wbuild_kernel(const float* __restrict__ experts,
                                                     const float* __restrict__ logits,
                                                     __bf16* __restrict__ wf) {
  int o = blockIdx.x;      // 0..255
  int tid = threadIdx.x;
  __shared__ float sf[3][2304];  // folded experts [e][c*9+tap] (27.6 KB)
  __shared__ float g[8][3];

#pragma unroll
  for (int e = 0; e < 3; e++) {
    const float4* src = (const float4*)(experts + ((size_t)e * 256 + o) * 4608);
    float4* dstp = (float4*)sf[e];
    for (int i = tid; i < 576; i += 256) {
      float4 a = src[i], bq = src[i + 576];
      float4 r;
      r.x = a.x + bq.x; r.y = a.y + bq.y; r.z = a.z + bq.z; r.w = a.w + bq.w;
      dstp[i] = r;
    }
  }
  if (tid < 8) {
    float l0 = logits[tid * 3 + 0], l1 = logits[tid * 3 + 1], l2 = logits[tid * 3 + 2];
    float m = fmaxf(l0, fmaxf(l1, l2));
    float e0 = __expf(l0 - m), e1 = __expf(l1 - m), e2 = __expf(l2 - m);
    float inv = 1.f / (e0 + e1 + e2);
    g[tid][0] = e0 * inv; g[tid][1] = e1 * inv; g[tid][2] = e2 * inv;
  }
  __syncthreads();

  int cl = tid & 31, ch = tid >> 5;   // c = tid
#pragma unroll 1
  for (int b = 0; b < 8; b++) {
    float g0 = g[b][0], g1 = g[b][1], g2 = g[b][2];
#pragma unroll
    for (int tap = 0; tap < 9; tap++) {
      float v = g0 * sf[0][tid * 9 + tap] + g1 * sf[1][tid * 9 + tap] +
                g2 * sf[2][tid * 9 + tap];
      wf[((((size_t)b * 9 + tap) * 8 + ch) * 256 + o) * 32 + cl] = (__bf16)v;
    }
  }
}

// ---------------- kernel 4: qT (padded, transposed, bf16) ----------------
__global__ __launch_bounds__(256) void qt_kernel(const float* __restrict__ q,
                                                 __bf16* __restrict__ qT) {
  int bid = blockIdx.x;          // (b*8 + ch)*66 + hp
  int hp = bid % 66;
  int t2 = bid / 66;
  int ch = t2 & 7;
  int b = t2 >> 3;
  __bf16* dst = qT + (((size_t)(b * 8 + ch) * 66 + hp) * 66) * 32;
  int tid = threadIdx.x;
  float4 z4 = {0.f, 0.f, 0.f, 0.f};
  if (hp == 0 || hp == 65) {     // top/bottom zero padding rows
    float4* d4 = (float4*)dst;
    for (int i = tid; i < 264; i += 256) d4[i] = z4;
    return;
  }
  __shared__ float tile2[64][33];  // [w][c]
  int h = hp - 1;
  {
    int w = tid & 63, ci = tid >> 6;
#pragma unroll
    for (int j = 0; j < 8; j++) {
      int c = ci * 8 + j;
      tile2[w][c] = q[(((size_t)b * 256 + ch * 32 + c) * 64 + h) * 64 + w];
    }
  }
  if (tid < 4) ((float4*)dst)[tid] = z4;                       // wp = 0
  else if (tid < 8) ((float4*)(dst + 65 * 32))[tid - 4] = z4;  // wp = 65
  __syncthreads();

  int a = tid & 7, wsl = tid >> 3;
  int cl4 = a * 4;
#pragma unroll
  for (int k = 0; k < 2; k++) {
    int w = wsl * 2 + k, wp = w + 1;
    int clp4 = (((cl4 >> 3) ^ ((wp >> 1) & 3)) << 3) | (cl4 & 7);
    float v0 = tile2[w][cl4 + 0], v1 = tile2[w][cl4 + 1];
    float v2 = tile2[w][cl4 + 2], v3 = tile2[w][cl4 + 3];
    bf16x4 r = {(__bf16)v0, (__bf16)v1, (__bf16)v2, (__bf16)v3};
    *(bf16x4*)(dst + wp * 32 + clp4) = r;
  }
}

// ---------------- kernel 5: MFMA conv — pipelined (A depth-2, B depth-1) ----------------
__global__ __launch_bounds__(256, 2) void conv_kernel(const __bf16* __restrict__ qT,
                                                      const __bf16* __restrict__ wf,
                                                      float* __restrict__ out) {
  __shared__ __align__(16) __bf16 Qlds[2][4 * 66 * 32];  // 2 x 16.9 KB
  const int tid = threadIdx.x;
  const int lane = tid & 63;
  const int wv = tid >> 6;
  const int wm = wv >> 1, wn = wv & 1;
  const int l15 = lane & 15, qd = lane >> 4;

  const int bid = blockIdx.x;
  const int b = bid & 7;            // XCD swizzle
  const int rem = bid >> 3;         // 0..63
  const int o0 = (rem >> 5) * 128;
  const int h0 = (rem & 31) * 2;

  f32x4 acc[4][4];
  {
    f32x4 z = {0.f, 0.f, 0.f, 0.f};
#pragma unroll
    for (int i = 0; i < 4; i++)
#pragma unroll
      for (int j = 0; j < 4; j++) acc[i][j] = z;
  }

  // B-offset table: btab[dw][ni] = ((wp)*32 + g)*2, wp = ni*16+l15+dw
  int btab[3][4];
#pragma unroll
  for (int dw = 0; dw < 3; dw++)
#pragma unroll
    for (int ni = 0; ni < 4; ni++) {
      int wp = ni * 16 + l15 + dw;
      int g = (qd ^ ((wp >> 1) & 3)) << 3;
      btab[dw][ni] = (wp * 32 + g) * 2;
    }

  const char* qT_b = (const char*)qT + (size_t)b * 8 * 66 * 66 * 32 * 2;
  const char* abase = (const char*)wf + ((size_t)b * 9 * 8 * 256 +
                                         (size_t)(o0 + wm * 64 + l15)) * 64 +
                      (size_t)qd * 16;
  // A pipeline: depth 2. a_reg[(s)%3] holds A(step s).
  bf16x8 areg[3][4];
  // B pipeline: depth 1 within a ch.
  bf16x8 breg[2][4];

  // ---- prologue: stage Q(ch=0); load A(s=0), A(s=1)
  {
    const char* qsrc = qT_b + ((size_t)h0) * 4224;
    for (int i = tid; i < 1056; i += 256) {
      int ub = i - lane;
      __builtin_amdgcn_global_load_lds((const AS1 void*)(qsrc + ((size_t)i << 4)),
                                       (AS3 void*)((char*)Qlds[0] + ((size_t)ub << 4)),
                                       16, 0, 0);
    }
#pragma unroll
    for (int mi = 0; mi < 4; mi++) {
      areg[0][mi] = *(const bf16x8*)(abase + ((size_t)(0 * 8 + 0) << 14) + mi * 1024);
      areg[1][mi] = *(const bf16x8*)(abase + ((size_t)(1 * 8 + 0) << 14) + mi * 1024);
    }
    __syncthreads();  // Q0 staged
    // load B(ch0, tap0): dh=0,dw=0, r=wn
#pragma unroll
    for (int ni = 0; ni < 4; ni++)
      breg[0][ni] = *(const bf16x8*)((const char*)Qlds[0] + wn * 4224 + btab[0][ni]);
  }

#pragma unroll 1
  for (int ch = 0; ch < 8; ch++) {
    if (ch < 7) {  // prefetch next ch's Q rows — overlaps all 9 taps
      const char* qsrc = qT_b + ((size_t)((ch + 1) * 66 + h0)) * 4224;
      char* qdst = (char*)Qlds[(ch + 1) & 1];
      for (int i = tid; i < 1056; i += 256) {
        int ub = i - lane;
        __builtin_amdgcn_global_load_lds((const AS1 void*)(qsrc + ((size_t)i << 4)),
                                         (AS3 void*)(qdst + ((size_t)ub << 4)),
                                         16, 0, 0);
      }
    }
    const char* Qb = (const char*)Qlds[ch & 1];
#pragma unroll
    for (int tap = 0; tap < 9; tap++) {
      const int s = ch * 9 + tap;
      // A prefetch, 2 steps ahead (register ring slot (s+2)%3)
      {
        int s2 = s + 2;
        int ch2 = s2 / 9, tap2 = s2 - ch2 * 9;
        if (ch2 > 7) { ch2 = 0; tap2 = 0; }   // clamped dummy, never used
        size_t aoff = ((size_t)(tap2 * 8 + ch2)) << 14;
#pragma unroll
        for (int mi = 0; mi < 4; mi++)
          areg[(s + 2) % 3][mi] = *(const bf16x8*)(abase + aoff + mi * 1024);
      }
      // B prefetch, 1 step ahead within this ch
      if (tap < 8) {
        int tapn = tap + 1;
        int dhn = tapn / 3, dwn = tapn - dhn * 3;
        int rbn = (wn + dhn) * 4224;
#pragma unroll
        for (int ni = 0; ni < 4; ni++)
          breg[(tap + 1) & 1][ni] = *(const bf16x8*)(Qb + rbn + btab[dwn][ni]);
      }
      // MFMA on current regs
#pragma unroll
      for (int ni = 0; ni < 4; ni++)
#pragma unroll
        for (int mi = 0; mi < 4; mi++)
          acc[mi][ni] = __builtin_amdgcn_mfma_f32_16x16x32_bf16(
              areg[s % 3][mi], breg[tap & 1][ni], acc[mi][ni], 0, 0, 0);
    }
    __syncthreads();  // Q(ch+1) staged+drained; buffer reuse safe
    if (ch < 7) {     // load B(ch+1, tap0) from the freshly staged buffer
      const char* Qn = (const char*)Qlds[(ch + 1) & 1];
#pragma unroll
      for (int ni = 0; ni < 4; ni++)
        breg[0][ni] = *(const bf16x8*)(Qn + wn * 4224 + btab[0][ni]);
    }
  }

  // epilogue: C/D layout col = lane&15 (w), row = qd*4+rr (o)
  const int hh = h0 + wn;
#pragma unroll
  for (int mi = 0; mi < 4; mi++) {
    int o = o0 + wm * 64 + mi * 16 + qd * 4;
#pragma unroll
    for (int ni = 0; ni < 4; ni++) {
      int w = ni * 16 + l15;
#pragma unroll
      for (int rr = 0; rr < 4; rr++)
        out[(((size_t)b * 256 + (o + rr)) * 64 + hh) * 64 + w] = acc[mi][ni][rr];
    }
  }
}

extern "C" void kernel_launch(void* const* d_in, const int* in_sizes, int n_in,
                              void* d_out, int out_size, void* d_ws, size_t ws_size,
                              hipStream_t stream) {
  (void)in_sizes; (void)n_in; (void)out_size; (void)ws_size;
  const float* q = (const float*)d_in[0];
  const float* y = (const float*)d_in[1];
  const float* experts = (const float*)d_in[2];
  const float* gate_w = (const float*)d_in[3];
  const float* gate_b = (const float*)d_in[4];
  float* out = (float*)d_out;

  char* ws = (char*)d_ws;
  float* yctx = (float*)ws;                         // 8 KB
  float* logits = (float*)(ws + 8192);              // 96 B
  __bf16* wf = (__bf16*)(ws + 16384);               // 9,437,184 B
  __bf16* qT = (__bf16*)(ws + 16384 + 9437184);     // 17,842,176 B

  yctx_kernel<<<2048, 64, 0, stream>>>(y, yctx);
  logits_kernel<<<24, 64, 0, stream>>>(yctx, gate_w, gate_b, logits);
  qt_kernel<<<8 * 8 * 66, 256, 0, stream>>>(q, qT);
  wbuild_kernel<<<256, 256, 0, stream>>>(experts, logits, wf);
  conv_kernel<<<512, 256, 0, stream>>>(qT, wf, out);
}

// Round 6
// 181.637 us; speedup vs baseline: 1.0490x; 1.0070x over previous
//
#include <hip/hip_runtime.h>
#include <hip/hip_bf16.h>
#include <math.h>

// Problem constants (B,C,H,W,O,K,E) = (8,256,64,64,256,3,3)
// weff[b,o,c,tap] = sum_e gates[b,e]*(experts[e,o,c,tap]+experts[e,o,c+256,tap])
// out[b,o,h,w] = sum_{c,dh,dw} q[b,c,h+dh-1,w+dw-1] * weff[b,o,c,dh*3+dw]
//
// Workspace (~27.3 MB):
//   [0)        yctx   : 2048 f32
//   [16384)    wf     : bf16 [8 b][9 tap][8 ch][256 o][32 c]   (unswizzled)
//   [9453568)  qT     : bf16 [8 b][8 ch][66 hp][66 wp][32 cl']
// qT cl' swizzle: group' = (cl>>3) ^ ((wp>>1)&3) -> ds_read_b128 conflict-free.
//
// conv R6: same block/LDS structure as R5 (128x128 tile, 4 waves M64xN64,
// grid 512 = 2 blk/CU, 1 barrier/ch, A reg-ring depth-2, B prefetch depth-1)
// but MFMA shape 32x32x16 -> 8 MFMA-instrs/step (was 16), same operand bytes.
// Theory: ~6 cyc/instr un-modeled per-wave overhead; halving instrs attacks it.

typedef __bf16 bf16x8 __attribute__((ext_vector_type(8)));
typedef __bf16 bf16x4 __attribute__((ext_vector_type(4)));
typedef float f32x4 __attribute__((ext_vector_type(4)));
typedef float f32x16 __attribute__((ext_vector_type(16)));

#define AS1 __attribute__((address_space(1)))
#define AS3 __attribute__((address_space(3)))

// ---------------- kernel 1: qt (4224 blocks) + yctx (512 blocks) fused ----------------
__global__ __launch_bounds__(256) void prep_kernel(const float* __restrict__ q,
                                                   const float* __restrict__ y,
                                                   __bf16* __restrict__ qT,
                                                   float* __restrict__ yctx) {
  int bid = blockIdx.x;
  int tid = threadIdx.x;
  if (bid >= 4224) {   // ---- yctx role: wave wv reduces one (b,c) plane
    int wv = tid >> 6, lane = tid & 63;
    int bc = (bid - 4224) * 4 + wv;   // 0..2047
    const float4* p = (const float4*)(y + (size_t)bc * 4096);
    float s = 0.f;
    for (int i = lane; i < 1024; i += 64) {
      float4 v = p[i];
      s += v.x + v.y + v.z + v.w;
    }
#pragma unroll
    for (int off = 32; off > 0; off >>= 1) s += __shfl_down(s, off, 64);
    if (lane == 0) yctx[bc] = s * (1.f / 4096.f);
    return;
  }
  // ---- qt role: (b*8 + ch)*66 + hp
  int hp = bid % 66;
  int t2 = bid / 66;
  int ch = t2 & 7;
  int b = t2 >> 3;
  __bf16* dst = qT + (((size_t)(b * 8 + ch) * 66 + hp) * 66) * 32;
  float4 z4 = {0.f, 0.f, 0.f, 0.f};
  if (hp == 0 || hp == 65) {     // top/bottom zero padding rows
    float4* d4 = (float4*)dst;
    for (int i = tid; i < 264; i += 256) d4[i] = z4;
    return;
  }
  __shared__ float tile2[64][33];  // [w][c]
  int h = hp - 1;
  {
    int w = tid & 63, ci = tid >> 6;
#pragma unroll
    for (int j = 0; j < 8; j++) {
      int c = ci * 8 + j;
      tile2[w][c] = q[(((size_t)b * 256 + ch * 32 + c) * 64 + h) * 64 + w];
    }
  }
  if (tid < 4) ((float4*)dst)[tid] = z4;                       // wp = 0
  else if (tid < 8) ((float4*)(dst + 65 * 32))[tid - 4] = z4;  // wp = 65
  __syncthreads();

  int a = tid & 7, wsl = tid >> 3;
  int cl4 = a * 4;
#pragma unroll
  for (int k = 0; k < 2; k++) {
    int w = wsl * 2 + k, wp = w + 1;
    int clp4 = (((cl4 >> 3) ^ ((wp >> 1) & 3)) << 3) | (cl4 & 7);
    float v0 = tile2[w][cl4 + 0], v1 = tile2[w][cl4 + 1];
    float v2 = tile2[w][cl4 + 2], v3 = tile2[w][cl4 + 3];
    bf16x4 r = {(__bf16)v0, (__bf16)v1, (__bf16)v2, (__bf16)v3};
    *(bf16x4*)(dst + wp * 32 + clp4) = r;
  }
}

// ---------------- kernel 2: wbuild with fused gate computation ----------------
__global__ __launch_bounds__(256) void wbuild_kernel(const float* __restrict__ experts,
                                                     const float* __restrict__ yctx,
                                                     const float* __restrict__ gw,
                                                     const float* __restrict__ gb,
                                                     __bf16* __restrict__ wf) {
  int o = blockIdx.x;      // 0..255
  int tid = threadIdx.x;
  __shared__ float sf[3][2304];    // folded experts [e][c*9+tap] (27.6 KB)
  __shared__ float lgpart[4][24];
  __shared__ float g[8][3];

  // issue the big expert loads first (overlap with gate math below)
#pragma unroll
  for (int e = 0; e < 3; e++) {
    const float4* src = (const float4*)(experts + ((size_t)e * 256 + o) * 4608);
    float4* dstp = (float4*)sf[e];
    for (int i = tid; i < 576; i += 256) {
      float4 a = src[i], bq = src[i + 576];
      float4 r;
      r.x = a.x + bq.x; r.y = a.y + bq.y; r.z = a.z + bq.z; r.w = a.w + bq.w;
      dstp[i] = r;
    }
  }
  // gates: thread t owns c=t; 24 partials; wave shfl-reduce; cross-wave via LDS
  {
    int c = tid;
    float gwf[3], yc[8];
#pragma unroll
    for (int e = 0; e < 3; e++) gwf[e] = gw[c * 3 + e] + gw[(c + 256) * 3 + e];
#pragma unroll
    for (int b = 0; b < 8; b++) yc[b] = yctx[b * 256 + c];
    int wv = tid >> 6, lane = tid & 63;
#pragma unroll
    for (int b = 0; b < 8; b++)
#pragma unroll
      for (int e = 0; e < 3; e++) {
        float s = yc[b] * gwf[e];
#pragma unroll
        for (int off = 32; off > 0; off >>= 1) s += __shfl_down(s, off, 64);
        if (lane == 0) lgpart[wv][b * 3 + e] = s;
      }
  }
  __syncthreads();
  if (tid < 24) {
    int e = tid % 3;
    float s = lgpart[0][tid] + lgpart[1][tid] + lgpart[2][tid] + lgpart[3][tid] + gb[e];
    lgpart[0][tid] = s;
  }
  __syncthreads();
  if (tid < 8) {
    float l0 = lgpart[0][tid * 3 + 0], l1 = lgpart[0][tid * 3 + 1],
          l2 = lgpart[0][tid * 3 + 2];
    float m = fmaxf(l0, fmaxf(l1, l2));
    float e0 = __expf(l0 - m), e1 = __expf(l1 - m), e2 = __expf(l2 - m);
    float inv = 1.f / (e0 + e1 + e2);
    g[tid][0] = e0 * inv; g[tid][1] = e1 * inv; g[tid][2] = e2 * inv;
  }
  __syncthreads();

  int cl = tid & 31, ch = tid >> 5;   // c = tid
#pragma unroll 1
  for (int b = 0; b < 8; b++) {
    float g0 = g[b][0], g1 = g[b][1], g2 = g[b][2];
#pragma unroll
    for (int tap = 0; tap < 9; tap++) {
      float v = g0 * sf[0][tid * 9 + tap] + g1 * sf[1][tid * 9 + tap] +
                g2 * sf[2][tid * 9 + tap];
      wf[((((size_t)b * 9 + tap) * 8 + ch) * 256 + o) * 32 + cl] = (__bf16)v;
    }
  }
}

// ---------------- kernel 3: MFMA conv — 32x32x16, pipelined ----------------
__global__ __launch_bounds__(256, 2) void conv_kernel(const __bf16* __restrict__ qT,
                                                      const __bf16* __restrict__ wf,
                                                      float* __restrict__ out) {
  __shared__ __align__(16) __bf16 Qlds[2][4 * 66 * 32];  // 2 x 16.9 KB
  const int tid = threadIdx.x;
  const int lane = tid & 63;
  const int wv = tid >> 6;
  const int wm = wv >> 1, wn = wv & 1;   // wm: o-half(64), wn: h-row
  const int l31 = lane & 31, hi = lane >> 5;

  const int bid = blockIdx.x;
  const int b = bid & 7;            // XCD swizzle
  const int rem = bid >> 3;         // 0..63
  const int o0 = (rem >> 5) * 128;
  const int h0 = (rem & 31) * 2;

  f32x16 acc[2][2];
  {
    f32x16 z = {0.f};
#pragma unroll
    for (int i = 0; i < 2; i++)
#pragma unroll
      for (int j = 0; j < 2; j++) acc[i][j] = z;
  }

  // B-offset table: [dw][nt][kh] = wp*64 + swizzled 16B group
  //   wp = nt*32 + l31 + dw; c-group = (kh*2 + hi) ^ ((wp>>1)&3)
  int bofs[3][2][2];
#pragma unroll
  for (int dw = 0; dw < 3; dw++)
#pragma unroll
    for (int nt = 0; nt < 2; nt++) {
      int wp = nt * 32 + l31 + dw;
      int sw = (wp >> 1) & 3;
#pragma unroll
      for (int kh = 0; kh < 2; kh++)
        bofs[dw][nt][kh] = wp * 64 + (((kh * 2 + hi) ^ sw) << 4);
    }

  const char* qT_b = (const char*)qT + (size_t)b * 8 * 66 * 66 * 32 * 2;
  // A frag [mt][kh]: m = l31 (o-row), k = kh*16 + hi*8 + j
  const char* abase = (const char*)wf + ((size_t)b * 9 * 8 * 256 +
                                         (size_t)(o0 + wm * 64 + l31)) * 64 +
                      (size_t)hi * 16;
  bf16x8 areg[3][4];   // ring slot s%3, frag idx = mt*2+kh
  bf16x8 breg[2][4];   // tap parity,  frag idx = kh*2+nt

  // ---- prologue: stage Q(ch=0); load A(s=0), A(s=1)
  {
    const char* qsrc = qT_b + ((size_t)h0) * 4224;
    for (int i = tid; i < 1056; i += 256) {
      int ub = i - lane;
      __builtin_amdgcn_global_load_lds((const AS1 void*)(qsrc + ((size_t)i << 4)),
                                       (AS3 void*)((char*)Qlds[0] + ((size_t)ub << 4)),
                                       16, 0, 0);
    }
#pragma unroll
    for (int mt = 0; mt < 2; mt++)
#pragma unroll
      for (int kh = 0; kh < 2; kh++) {
        areg[0][mt * 2 + kh] = *(const bf16x8*)(abase + mt * 2048 + kh * 32);
        areg[1][mt * 2 + kh] =
            *(const bf16x8*)(abase + ((size_t)8 << 14) + mt * 2048 + kh * 32);
      }
    __syncthreads();
#pragma unroll
    for (int kh = 0; kh < 2; kh++)
#pragma unroll
      for (int nt = 0; nt < 2; nt++)
        breg[0][kh * 2 + nt] =
            *(const bf16x8*)((const char*)Qlds[0] + wn * 4224 + bofs[0][nt][kh]);
  }

#pragma unroll 1
  for (int ch = 0; ch < 8; ch++) {
    if (ch < 7) {  // prefetch next ch's Q rows — overlaps all 9 taps
      const char* qsrc = qT_b + ((size_t)((ch + 1) * 66 + h0)) * 4224;
      char* qdst = (char*)Qlds[(ch + 1) & 1];
      for (int i = tid; i < 1056; i += 256) {
        int ub = i - lane;
        __builtin_amdgcn_global_load_lds((const AS1 void*)(qsrc + ((size_t)i << 4)),
                                         (AS3 void*)(qdst + ((size_t)ub << 4)),
                                         16, 0, 0);
      }
    }
    const char* Qb = (const char*)Qlds[ch & 1];
#pragma unroll
    for (int tap = 0; tap < 9; tap++) {
      const int s = ch * 9 + tap;
      {  // A prefetch, 2 steps ahead
        int s2 = s + 2;
        int ch2 = s2 / 9, tap2 = s2 - ch2 * 9;
        if (ch2 > 7) { ch2 = 0; tap2 = 0; }   // clamped dummy, never used
        size_t aoff = ((size_t)(tap2 * 8 + ch2)) << 14;
#pragma unroll
        for (int mt = 0; mt < 2; mt++)
#pragma unroll
          for (int kh = 0; kh < 2; kh++)
            areg[(s + 2) % 3][mt * 2 + kh] =
                *(const bf16x8*)(abase + aoff + mt * 2048 + kh * 32);
      }
      if (tap < 8) {  // B prefetch, 1 step ahead within this ch
        int tapn = tap + 1;
        int dhn = tapn / 3, dwn = tapn - dhn * 3;
        int rbn = (wn + dhn) * 4224;
#pragma unroll
        for (int kh = 0; kh < 2; kh++)
#pragma unroll
          for (int nt = 0; nt < 2; nt++)
            breg[(tap + 1) & 1][kh * 2 + nt] =
                *(const bf16x8*)(Qb + rbn + bofs[dwn][nt][kh]);
      }
      // 8 MFMAs on current regs
#pragma unroll
      for (int kh = 0; kh < 2; kh++)
#pragma unroll
        for (int nt = 0; nt < 2; nt++)
#pragma unroll
          for (int mt = 0; mt < 2; mt++)
            acc[mt][nt] = __builtin_amdgcn_mfma_f32_32x32x16_bf16(
                areg[s % 3][mt * 2 + kh], breg[tap & 1][kh * 2 + nt],
                acc[mt][nt], 0, 0, 0);
    }
    __syncthreads();  // Q(ch+1) staged+drained; buffer reuse safe
    if (ch < 7) {     // B(ch+1, tap0) from freshly staged buffer
      const char* Qn = (const char*)Qlds[(ch + 1) & 1];
#pragma unroll
      for (int kh = 0; kh < 2; kh++)
#pragma unroll
        for (int nt = 0; nt < 2; nt++)
          breg[0][kh * 2 + nt] =
              *(const bf16x8*)(Qn + wn * 4224 + bofs[0][nt][kh]);
    }
  }

  // epilogue: 32x32 C/D layout: col = lane&31 (w), row = (r&3)+8*(r>>2)+4*hi (o)
  const int hh = h0 + wn;
#pragma unroll
  for (int mt = 0; mt < 2; mt++) {
    int ob = o0 + wm * 64 + mt * 32 + 4 * hi;
#pragma unroll
    for (int nt = 0; nt < 2; nt++) {
      int w = nt * 32 + l31;
#pragma unroll
      for (int r = 0; r < 16; r++) {
        int o = ob + (r & 3) + 8 * (r >> 2);
        out[(((size_t)b * 256 + o) * 64 + hh) * 64 + w] = acc[mt][nt][r];
      }
    }
  }
}

extern "C" void kernel_launch(void* const* d_in, const int* in_sizes, int n_in,
                              void* d_out, int out_size, void* d_ws, size_t ws_size,
                              hipStream_t stream) {
  (void)in_sizes; (void)n_in; (void)out_size; (void)ws_size;
  const float* q = (const float*)d_in[0];
  const float* y = (const float*)d_in[1];
  const float* experts = (const float*)d_in[2];
  const float* gate_w = (const float*)d_in[3];
  const float* gate_b = (const float*)d_in[4];
  float* out = (float*)d_out;

  char* ws = (char*)d_ws;
  float* yctx = (float*)ws;                         // 8 KB
  __bf16* wf = (__bf16*)(ws + 16384);               // 9,437,184 B
  __bf16* qT = (__bf16*)(ws + 16384 + 9437184);     // 17,842,176 B

  prep_kernel<<<4224 + 512, 256, 0, stream>>>(q, y, qT, yctx);
  wbuild_kernel<<<256, 256, 0, stream>>>(experts, yctx, gate_w, gate_b, wf);
  conv_kernel<<<512, 256, 0, stream>>>(qT, wf, out);
}